// Round 6
// baseline (236.930 us; speedup 1.0000x reference)
//
#include <hip/hip_runtime.h>
#include <hip/hip_bf16.h>
#include <stdint.h>

// GroupTorchGRU: B=1024, U=8, I=H=512, fp32 in/out.
// R6: K1 prepass (fp32->bf16 into d_ws) + K2 fused GEMM+gates with
//  - BM=128 x BN=64 tile, 512 blocks, 512 threads (gate-split: waves 0-3 gx,
//    waves 4-7 gh), 24 MFMA per wave per K-iter (2x R5 density)
//  - double-buffered global_load_lds pipeline, BK=32, 2x40KB LDS
//  - proven 128B-line XOR swizzle (R5 measured 0 bank conflicts)
//  - lane-matched gh->gx epilogue exchange in 4 per-mt rounds (24KB each)
//  - XCD-aware grid: id%8 = nb so each XCD's weight set is L2-resident
// Fallback: R3 single-kernel path if ws too small.

#define B_ 1024
#define U_ 8
#define I_ 512
#define H_ 512
#define KDIM 512

#define NX (B_ * U_ * I_)
#define NW (U_ * 3 * H_ * I_)
#define OFF_X 0
#define OFF_H NX
#define OFF_WIH (2 * NX)
#define OFF_WHH (2 * NX + NW)
#define NTOT (2 * NX + 2 * NW)
#define WS_NEED ((size_t)NTOT * 2)

#define BM 128
#define BN 64
#define BK 32
#define NITER (KDIM / BK)        // 16
#define BUF_B 40960              // X 8KB + H 8KB + 6 x 4KB weights
#define ESTR 68                  // fallback epilogue stride

typedef __attribute__((ext_vector_type(8))) short short8;
typedef __attribute__((ext_vector_type(4))) float floatx4;

__device__ __forceinline__ unsigned int pk2bf(float a, float b) {
    float2 f2; f2.x = a; f2.y = b;
    union { __hip_bfloat162 h; unsigned int u; } cv;
    cv.h = __float22bfloat162_rn(f2);
    return cv.u;
}

__device__ __forceinline__ void async16(const void* g, void* l) {
    __builtin_amdgcn_global_load_lds(
        (const __attribute__((address_space(1))) void*)g,
        (__attribute__((address_space(3))) void*)l, 16, 0, 0);
}

// ---------------- K1: fp32 -> bf16 prepass ----------------
__global__ __launch_bounds__(256)
void convert_bf16_kernel(const float* __restrict__ x, const float* __restrict__ h,
                         const float* __restrict__ wih, const float* __restrict__ whh,
                         unsigned short* __restrict__ ws)
{
    const size_t base = ((size_t)blockIdx.x * 256 + threadIdx.x) * 8;
    const float* src; size_t off;
    if (base < (size_t)OFF_H)        { src = x;   off = OFF_X; }
    else if (base < (size_t)OFF_WIH) { src = h;   off = OFF_H; }
    else if (base < (size_t)OFF_WHH) { src = wih; off = OFF_WIH; }
    else                             { src = whh; off = OFF_WHH; }
    const float4 v0 = *(const float4*)(src + (base - off));
    const float4 v1 = *(const float4*)(src + (base - off) + 4);
    uint4 o;
    o.x = pk2bf(v0.x, v0.y);
    o.y = pk2bf(v0.z, v0.w);
    o.z = pk2bf(v1.x, v1.y);
    o.w = pk2bf(v1.z, v1.w);
    *(uint4*)(ws + base) = o;
}

// ---------------- K2: fused bf16 GEMM + GRU gates ----------------
// Buffer layout (40KB): X slab [0,8K) 128r x 32k; H slab [8K,16K);
// weight slabs w=0..5 at 16K + w*4K, 64r x 32k.
// Within a slab: 128B "line" = 2 rows x 4 chunks of 16B; physical 16B slot p
// of line L holds logical slot p ^ (L&7), logical slot = (row&1)*4 + kchunk.
__global__ __launch_bounds__(512, 4)
void gru_main_kernel(const unsigned short* __restrict__ ws,
                     const float* __restrict__ hidden,
                     const float* __restrict__ b_ih,
                     const float* __restrict__ b_hh,
                     float* __restrict__ out)
{
    const int u  = blockIdx.x >> 3;   // id%8 = nb -> XCD-local weights
    const int nb = blockIdx.x & 7;
    const int mb = blockIdx.y;        // 0..7
    const int b0 = mb * BM;
    const int h0 = nb * BN;

    const int tid  = threadIdx.x;
    const int lane = tid & 63;
    const int wave = tid >> 6;        // 0..7
    const int lr   = lane & 15;
    const int q    = lane >> 4;
    const int p    = wave & 3;        // quadrant within gate-group
    const int wm   = p & 1;           // 64-row half
    const int wn   = p >> 1;          // 32-col half
    const int g2   = wave >> 2;       // 0: gx, 1: gh

    __shared__ __align__(16) char smem[2 * BUF_B];   // 80KB

    // ---- staging: 40 x 1KB instrs per buffer, 5 per wave ----
    const unsigned short* baseX = ws + OFF_X + ((size_t)b0 * U_ + u) * I_;
    const unsigned short* baseH = ws + OFF_H + ((size_t)b0 * U_ + u) * H_;
    const unsigned short* wb[6];
    #pragma unroll
    for (int w = 0; w < 3; ++w) {
        wb[w]     = ws + OFF_WIH + ((size_t)(u * 3 + w) * H_ + h0) * I_;
        wb[w + 3] = ws + OFF_WHH + ((size_t)(u * 3 + w) * H_ + h0) * H_;
    }

    const unsigned short* gptr[5];
    int ldsoff[5];
    #pragma unroll
    for (int i = 0; i < 5; ++i) {
        const int j = wave * 5 + i;
        const unsigned short* sbase; int rstr, group, soff;
        if (j < 8)       { sbase = baseX;          rstr = U_ * I_; group = j;            soff = 0; }
        else if (j < 16) { sbase = baseH;          rstr = U_ * H_; group = j - 8;        soff = 8192; }
        else             { const int w = (j - 16) >> 2;
                           sbase = wb[w];          rstr = I_;      group = (j - 16) & 3; soff = 16384 + w * 4096; }
        const int line = group * 8 + (lane >> 3);
        const int pos  = (lane & 7) ^ (line & 7);
        const int row  = 2 * line + (pos >> 2);
        const int ch   = pos & 3;
        gptr[i]   = sbase + (size_t)row * rstr + ch * 8;
        ldsoff[i] = soff + group * 1024 + lane * 16;
    }

    // ---- fragment read offsets (within-slab bytes) ----
    int aoff[4], boff[2];
    #pragma unroll
    for (int mt = 0; mt < 4; ++mt) {
        const int r = wm * 64 + mt * 16 + lr;
        const int line = r >> 1;
        const int pp = (((r & 1) * 4 + q)) ^ (line & 7);
        aoff[mt] = line * 128 + pp * 16;
    }
    #pragma unroll
    for (int nt = 0; nt < 2; ++nt) {
        const int r = wn * 32 + nt * 16 + lr;
        const int line = r >> 1;
        const int pp = (((r & 1) * 4 + q)) ^ (line & 7);
        boff[nt] = line * 128 + pp * 16;
    }

    floatx4 acc[3][4][2];
    #pragma unroll
    for (int g = 0; g < 3; ++g)
        #pragma unroll
        for (int mt = 0; mt < 4; ++mt)
            #pragma unroll
            for (int nt = 0; nt < 2; ++nt)
                acc[g][mt][nt] = (floatx4){0.f, 0.f, 0.f, 0.f};

    // ---- prologue: loads for buffer 0 ----
    #pragma unroll
    for (int i = 0; i < 5; ++i) {
        async16(gptr[i], smem + ldsoff[i]);
        gptr[i] += BK;
    }

    for (int it = 0; it < NITER; ++it) {
        const int cur = it & 1;
        __syncthreads();   // drains buf[cur] loads (in flight through prev MFMA)

        if (it + 1 < NITER) {
            const int nxt = ((it + 1) & 1) * BUF_B;
            #pragma unroll
            for (int i = 0; i < 5; ++i) {
                async16(gptr[i], smem + nxt + ldsoff[i]);
                gptr[i] += BK;
            }
        }

        const char* base  = smem + cur * BUF_B;
        const char* abase = base + g2 * 8192;     // X for gx, H for gh
        short8 a[4];
        #pragma unroll
        for (int mt = 0; mt < 4; ++mt)
            a[mt] = *(const short8*)(abase + aoff[mt]);
        #pragma unroll
        for (int g = 0; g < 3; ++g) {
            const char* bslab = base + 16384 + (g2 * 3 + g) * 4096;
            #pragma unroll
            for (int nt = 0; nt < 2; ++nt) {
                const short8 bf = *(const short8*)(bslab + boff[nt]);
                #pragma unroll
                for (int mt = 0; mt < 4; ++mt)
                    acc[g][mt][nt] = __builtin_amdgcn_mfma_f32_16x16x32_bf16(
                        a[mt], bf, acc[g][mt][nt], 0, 0, 0);
            }
        }
    }

    // ---- epilogue: 4 per-mt rounds; lane-matched gh->gx exchange ----
    // ep[t][p][lane], t = g*2+nt, float4 each: 6*4*64*16 = 24KB (reuses smem).
    float4* ep = (float4*)smem;
    const float* bih = b_ih + u * (3 * H_);
    const float* bhh = b_hh + u * (3 * H_);

    for (int m = 0; m < 4; ++m) {
        __syncthreads();   // first round: protects K-loop reads; later: ep reuse
        if (g2 == 1) {
            #pragma unroll
            for (int g = 0; g < 3; ++g)
                #pragma unroll
                for (int nt = 0; nt < 2; ++nt)
                    ep[((g * 2 + nt) * 4 + p) * 64 + lane] =
                        (float4){acc[g][m][nt][0], acc[g][m][nt][1],
                                 acc[g][m][nt][2], acc[g][m][nt][3]};
        }
        __syncthreads();
        if (g2 == 0) {
            #pragma unroll
            for (int nt = 0; nt < 2; ++nt) {
                const int col  = wn * 32 + nt * 16 + lr;
                const int hcol = h0 + col;
                const float bir  = bih[hcol],          bhr = bhh[hcol];
                const float biz  = bih[H_ + hcol],     bhz = bhh[H_ + hcol];
                const float bin_ = bih[2 * H_ + hcol], bhn = bhh[2 * H_ + hcol];
                const float4 hrv = ep[((0 * 2 + nt) * 4 + p) * 64 + lane];
                const float4 hzv = ep[((1 * 2 + nt) * 4 + p) * 64 + lane];
                const float4 hnv = ep[((2 * 2 + nt) * 4 + p) * 64 + lane];
                #pragma unroll
                for (int r = 0; r < 4; ++r) {
                    const int row = wm * 64 + m * 16 + q * 4 + r;
                    const size_t gidx = ((size_t)(b0 + row) * U_ + u) * H_ + hcol;
                    const float hprev = hidden[gidx];
                    const float hr = (r == 0 ? hrv.x : r == 1 ? hrv.y : r == 2 ? hrv.z : hrv.w) + bhr;
                    const float hz = (r == 0 ? hzv.x : r == 1 ? hzv.y : r == 2 ? hzv.z : hzv.w) + bhz;
                    const float hn = (r == 0 ? hnv.x : r == 1 ? hnv.y : r == 2 ? hnv.z : hnv.w) + bhn;
                    const float xr = acc[0][m][nt][r] + bir;
                    const float xz = acc[1][m][nt][r] + biz;
                    const float xn = acc[2][m][nt][r] + bin_;
                    const float rg = 1.f / (1.f + __expf(-(xr + hr)));
                    const float zg = 1.f / (1.f + __expf(-(xz + hz)));
                    const float ng = tanhf(xn + rg * hn);
                    out[gidx] = (1.f - zg) * ng + zg * hprev;
                }
            }
        }
    }
}

// ---------------- Fallback (R3, passed): used only if ws too small ----------------
#define LSTR 40
#define FBM 64
union SmemF {
    short bf[8][FBM * LSTR];
    float ep[3][FBM * ESTR];
};

__global__ __launch_bounds__(512, 4)
void gru_fallback_kernel(const float* __restrict__ inputs, const float* __restrict__ hidden,
                         const float* __restrict__ W_ih, const float* __restrict__ W_hh,
                         const float* __restrict__ b_ih, const float* __restrict__ b_hh,
                         float* __restrict__ out)
{
    const int nb = blockIdx.x;
    const int mb = blockIdx.y;
    const int u  = blockIdx.z;
    const int b0 = mb * FBM, h0 = nb * BN;
    const int tid = threadIdx.x, lane = tid & 63, wave = tid >> 6;
    const int lr = lane & 15, q = lane >> 4;
    const int wm = wave & 1, wn = (wave >> 1) & 1, g2 = wave >> 2;

    __shared__ SmemF smem;

    const float* srcs[8]; int rstr[8];
    srcs[0] = inputs + ((size_t)b0 * U_ + u) * I_;         rstr[0] = U_ * I_;
    srcs[1] = hidden + ((size_t)b0 * U_ + u) * H_;         rstr[1] = U_ * H_;
    srcs[2] = W_ih + ((size_t)(u * 3 + 0) * H_ + h0) * I_; rstr[2] = I_;
    srcs[3] = W_ih + ((size_t)(u * 3 + 1) * H_ + h0) * I_; rstr[3] = I_;
    srcs[4] = W_ih + ((size_t)(u * 3 + 2) * H_ + h0) * I_; rstr[4] = I_;
    srcs[5] = W_hh + ((size_t)(u * 3 + 0) * H_ + h0) * H_; rstr[5] = H_;
    srcs[6] = W_hh + ((size_t)(u * 3 + 1) * H_ + h0) * H_; rstr[6] = H_;
    srcs[7] = W_hh + ((size_t)(u * 3 + 2) * H_ + h0) * H_; rstr[7] = H_;

    const int srow = tid >> 3, c4 = (tid & 7) * 4;
    const float* tb[8];
    #pragma unroll
    for (int s = 0; s < 8; ++s) tb[s] = srcs[s] + (size_t)srow * rstr[s] + c4;

    floatx4 acc[3][2][2];
    #pragma unroll
    for (int g = 0; g < 3; ++g)
        #pragma unroll
        for (int mt = 0; mt < 2; ++mt)
            #pragma unroll
            for (int nt = 0; nt < 2; ++nt) acc[g][mt][nt] = (floatx4){0.f, 0.f, 0.f, 0.f};

    const int aslab = g2, bbase = 2 + 3 * g2;
    float4 pre[8];
    #pragma unroll
    for (int s = 0; s < 8; ++s) pre[s] = *(const float4*)(tb[s]);

    for (int k0 = 0; k0 < KDIM; k0 += 32) {
        #pragma unroll
        for (int s = 0; s < 8; ++s) {
            uint2 w; w.x = pk2bf(pre[s].x, pre[s].y); w.y = pk2bf(pre[s].z, pre[s].w);
            *(uint2*)&smem.bf[s][srow * LSTR + c4] = w;
        }
        __syncthreads();
        if (k0 + 32 < KDIM) {
            #pragma unroll
            for (int s = 0; s < 8; ++s) pre[s] = *(const float4*)(tb[s] + k0 + 32);
        }
        short8 afr[2];
        #pragma unroll
        for (int mt = 0; mt < 2; ++mt)
            afr[mt] = *(const short8*)&smem.bf[aslab][(wm * 32 + mt * 16 + lr) * LSTR + q * 8];
        #pragma unroll
        for (int g = 0; g < 3; ++g) {
            const short8 bf0 = *(const short8*)&smem.bf[bbase + g][(wn * 32 + lr) * LSTR + q * 8];
            const short8 bf1 = *(const short8*)&smem.bf[bbase + g][(wn * 32 + 16 + lr) * LSTR + q * 8];
            #pragma unroll
            for (int mt = 0; mt < 2; ++mt) {
                acc[g][mt][0] = __builtin_amdgcn_mfma_f32_16x16x32_bf16(afr[mt], bf0, acc[g][mt][0], 0, 0, 0);
                acc[g][mt][1] = __builtin_amdgcn_mfma_f32_16x16x32_bf16(afr[mt], bf1, acc[g][mt][1], 0, 0, 0);
            }
        }
        __syncthreads();
    }

    const float* bih = b_ih + u * (3 * H_);
    const float* bhh = b_hh + u * (3 * H_);
    if (g2 == 1) {
        #pragma unroll
        for (int nt = 0; nt < 2; ++nt) {
            const int col = wn * 32 + nt * 16 + lr;
            const float bhr = bhh[h0 + col], bhz = bhh[H_ + h0 + col], bhn = bhh[2 * H_ + h0 + col];
            #pragma unroll
            for (int mt = 0; mt < 2; ++mt)
                #pragma unroll
                for (int r = 0; r < 4; ++r) {
                    const int row = wm * 32 + mt * 16 + q * 4 + r;
                    smem.ep[0][row * ESTR + col] = acc[0][mt][nt][r] + bhr;
                    smem.ep[1][row * ESTR + col] = acc[1][mt][nt][r] + bhz;
                    smem.ep[2][row * ESTR + col] = acc[2][mt][nt][r] + bhn;
                }
        }
    }
    __syncthreads();
    if (g2 == 0) {
        #pragma unroll
        for (int nt = 0; nt < 2; ++nt) {
            const int col = wn * 32 + nt * 16 + lr, hcol = h0 + col;
            const float bir = bih[hcol], biz = bih[H_ + hcol], bin_ = bih[2 * H_ + hcol];
            #pragma unroll
            for (int mt = 0; mt < 2; ++mt)
                #pragma unroll
                for (int r = 0; r < 4; ++r) {
                    const int row = wm * 32 + mt * 16 + q * 4 + r;
                    const size_t gidx = ((size_t)(b0 + row) * U_ + u) * H_ + hcol;
                    const float hprev = hidden[gidx];
                    const float hr = smem.ep[0][row * ESTR + col];
                    const float hz = smem.ep[1][row * ESTR + col];
                    const float hn = smem.ep[2][row * ESTR + col];
                    const float xr = acc[0][mt][nt][r] + bir;
                    const float xz = acc[1][mt][nt][r] + biz;
                    const float xn = acc[2][mt][nt][r] + bin_;
                    const float rg = 1.f / (1.f + __expf(-(xr + hr)));
                    const float zg = 1.f / (1.f + __expf(-(xz + hz)));
                    const float ng = tanhf(xn + rg * hn);
                    out[gidx] = (1.f - zg) * ng + zg * hprev;
                }
        }
    }
}

extern "C" void kernel_launch(void* const* d_in, const int* in_sizes, int n_in,
                              void* d_out, int out_size, void* d_ws, size_t ws_size,
                              hipStream_t stream) {
    const float* inputs = (const float*)d_in[0];
    const float* hidden = (const float*)d_in[1];
    const float* W_ih   = (const float*)d_in[2];
    const float* W_hh   = (const float*)d_in[3];
    const float* b_ih   = (const float*)d_in[4];
    const float* b_hh   = (const float*)d_in[5];
    float* out = (float*)d_out;

    if (ws_size >= WS_NEED) {
        unsigned short* ws = (unsigned short*)d_ws;
        convert_bf16_kernel<<<NTOT / 2048, 256, 0, stream>>>(inputs, hidden, W_ih, W_hh, ws);
        dim3 grid(64, 8, 1);   // x = u*8+nb (id%8 = nb), y = mb (BM=128)
        gru_main_kernel<<<grid, 512, 0, stream>>>(ws, hidden, b_ih, b_hh, out);
    } else {
        dim3 grid(8, 16, 8);
        gru_fallback_kernel<<<grid, 512, 0, stream>>>(inputs, hidden, W_ih, W_hh, b_ih, b_hh, out);
    }
}